// Round 9
// baseline (1113.080 us; speedup 1.0000x reference)
//
#include <hip/hip_runtime.h>
#include <hip/hip_bf16.h>

#define D_DIM 512
#define S_LEN 12
#define H_NUM 8
#define WMAT 262144       // 512*512

// ---- kernel1: G_B=8, 96 rows, 12 waves ----
#define G_B1 8
#define ROWS1 96          // 6 M-tiles
#define THREADS1 768      // 12 waves: wave = (mat, colt)
#define QS 72             // Q/K row stride in u16 (144B: 16B-aligned, XOR-swizzled)
#define VS 102            // V col stride in u16 (204B, transposed [64][102])
#define X_OFF   0         // [96][512] bf16 = 98304
#define Q_OFF   98304     // [96][72] u16 = 13824
#define K_OFF   112128
#define V_OFF   125952    // [64][102] u16 = 13056 (transposed)
#define P_OFF   139008    // 8 x [12][20] f32 = 7680
#define SMEM1   146688    // 1 block/CU

// ---- kernel2: G_B=8, 1024 threads, 16 waves ----
#define G_B2 8
#define ROWS2 96
#define THREADS2 1024
#define AST_OFF 0         // [96][512] bf16 = 98304
#define RED_OFF 98304     // [96][33] f32 = 12672
#define MU_OFF  110976    // [96][2] f32 = 768
#define SMEM2   111744    // 1 block/CU, 16 waves

typedef __attribute__((ext_vector_type(8))) short bf16x8;
typedef __attribute__((ext_vector_type(4))) float f32x4;

__device__ __forceinline__ unsigned short f2bf(float f) {
    union { float f; unsigned u; } c; c.f = f;
    unsigned r = c.u + 0x7fffu + ((c.u >> 16) & 1u);
    return (unsigned short)(r >> 16);
}
__device__ __forceinline__ float bf2f(unsigned short u) {
    union { unsigned u; float f; } c; c.u = ((unsigned)u) << 16;
    return c.f;
}
// 16B-granule XOR swizzle, 512-col X tiles
__device__ __forceinline__ int xswc(int row, int col) {
    return row * 512 + (((col >> 3) ^ (row & 7)) << 3) + (col & 7);
}
// Q/K tiles: stride 72 u16 (16B-aligned rows) + 16B-chunk XOR
__device__ __forceinline__ int qsw72(int row, int col) {
    return row * QS + (((col >> 3) ^ (row & 7)) << 3) + (col & 7);
}

__global__ void prep_weights(const float* __restrict__ Wq, const float* __restrict__ Wk,
                             const float* __restrict__ Wv, const float* __restrict__ Wo,
                             unsigned short* __restrict__ wt) {
    int idx = blockIdx.x * 256 + threadIdx.x;   // 0 .. 4*WMAT-1
    int mat = idx >> 18;
    int rem = idx & (WMAT - 1);
    int e = rem >> 9, d = rem & 511;
    const float* W = (mat == 0) ? Wq : (mat == 1) ? Wk : (mat == 2) ? Wv : Wo;
    wt[idx] = f2bf(W[d * D_DIM + e]);           // wt[mat][e][d] = W[d][e]
}

// ---------------- kernel 1: QKV + attention -> A (f32, into d_out) ----------------
__global__ __launch_bounds__(THREADS1, 3) void qkv_attn(
    const float* __restrict__ x, const unsigned short* __restrict__ wt,
    const float* __restrict__ bq, const float* __restrict__ bk, const float* __restrict__ bv,
    const float* __restrict__ adj, float* __restrict__ aout)
{
    extern __shared__ char smem[];
    unsigned short* Xh = (unsigned short*)(smem + X_OFF);
    unsigned short* Qh = (unsigned short*)(smem + Q_OFF);   // [96][72] +xor
    unsigned short* Kh = (unsigned short*)(smem + K_OFF);   // [96][72] +xor
    unsigned short* Vt = (unsigned short*)(smem + V_OFF);   // [64][102] transposed
    float* Pl = (float*)(smem + P_OFF);         // [8][12][20]

    const int tid  = threadIdx.x;
    const int lane = tid & 63;
    const int w    = tid >> 6;          // wave 0..11
    const int lr   = lane & 15;
    const int lg   = lane >> 4;
    const int lr12 = (lr < 12) ? lr : 11;       // true clamp
    const size_t row0 = (size_t)blockIdx.x * ROWS1;

    // stage X -> LDS bf16 (swizzled)
    #pragma unroll
    for (int it = 0; it < 16; ++it) {
        int idx = it * THREADS1 + tid;
        int r = idx >> 7, col = (idx & 127) << 2;
        float4 v = *(const float4*)(x + (row0 + r) * (size_t)D_DIM + col);
        ushort4 pk;
        pk.x = f2bf(v.x); pk.y = f2bf(v.y); pk.z = f2bf(v.z); pk.w = f2bf(v.w);
        *(ushort4*)(Xh + xswc(r, col)) = pk;
    }
    __syncthreads();

    // wave task: mat = w>>2 (0=Q,1=K,2=V), colt = w&3
    const int mat  = w >> 2;
    const int colt = w & 3;
    const int colh = colt * 16 + lr;
    const float* bsel = (mat == 0) ? bq : (mat == 1) ? bk : bv;
    const int rb = w * S_LEN;                   // attention rows (waves 0-7)

    #pragma unroll 1
    for (int h = 0; h < H_NUM; ++h) {
        // ---------------- QKV projection for head h ----------------
        f32x4 acc[6];
        #pragma unroll
        for (int mt = 0; mt < 6; ++mt) acc[mt] = (f32x4){0.f, 0.f, 0.f, 0.f};

        const unsigned short* bAp = wt + (size_t)mat * WMAT + (h * 64 + colh) * D_DIM + lg * 8;
        bf16x8 bc = *(const bf16x8*)(bAp);      // B double-buffer: preload ks=0
        #pragma unroll
        for (int ks = 0; ks < 16; ++ks) {
            bf16x8 bn;
            if (ks < 15) bn = *(const bf16x8*)(bAp + (ks + 1) * 32);   // prefetch next
            #pragma unroll
            for (int mt = 0; mt < 6; ++mt) {
                bf16x8 af = *(const bf16x8*)(Xh + xswc(mt * 16 + lr, ks * 32 + lg * 8));
                acc[mt] = __builtin_amdgcn_mfma_f32_16x16x32_bf16(af, bc, acc[mt], 0, 0, 0);
            }
            if (ks < 15) bc = bn;
        }
        {
            float bias = bsel[h * 64 + colh];
            if (mat == 2) {
                // V: transposed store, 4 consecutive rows per lane -> 2x ushort2
                #pragma unroll
                for (int mt = 0; mt < 6; ++mt) {
                    int rbase = mt * 16 + lg * 4;
                    ushort2 p0, p1;
                    p0.x = f2bf(acc[mt][0] + bias); p0.y = f2bf(acc[mt][1] + bias);
                    p1.x = f2bf(acc[mt][2] + bias); p1.y = f2bf(acc[mt][3] + bias);
                    *(ushort2*)(Vt + colh * VS + rbase)     = p0;
                    *(ushort2*)(Vt + colh * VS + rbase + 2) = p1;
                }
            } else {
                unsigned short* T = (mat == 0) ? Qh : Kh;
                #pragma unroll
                for (int mt = 0; mt < 6; ++mt)
                    #pragma unroll
                    for (int j = 0; j < 4; ++j)
                        T[qsw72(mt * 16 + lg * 4 + j, colh)] = f2bf(acc[mt][j] + bias);
            }
        }
        __syncthreads();   // Q/K/V complete

        // ---------------- attention (waves 0-7 <-> batch items 0-7) ----------------
        if (w < 8) {
            f32x4 sacc = (f32x4){0.f, 0.f, 0.f, 0.f};
            #pragma unroll
            for (int k2 = 0; k2 < 2; ++k2) {
                bf16x8 ak = *(const bf16x8*)(Kh + qsw72(rb + lr12, k2 * 32 + lg * 8));
                bf16x8 aq = *(const bf16x8*)(Qh + qsw72(rb + lr12, k2 * 32 + lg * 8));
                sacc = __builtin_amdgcn_mfma_f32_16x16x32_bf16(ak, aq, sacc, 0, 0, 0);
            }
            float ab4[4] = {0.f, 0.f, 0.f, 0.f};
            if (lg < 3 && lr < 12) {
                float4 t4 = *(const float4*)(adj + (h * S_LEN + lr) * S_LEN + lg * 4);
                ab4[0] = t4.x; ab4[1] = t4.y; ab4[2] = t4.z; ab4[3] = t4.w;
            }
            float sc[4], e4[4];
            float m = -1e30f;
            #pragma unroll
            for (int j = 0; j < 4; ++j) {
                int t = lg * 4 + j;
                sc[j] = (t < 12) ? (sacc[j] * 0.125f + ab4[j]) : -1e30f;
                m = fmaxf(m, sc[j]);
            }
            m = fmaxf(m, __shfl_xor(m, 16));
            m = fmaxf(m, __shfl_xor(m, 32));
            float ssum = 0.f;
            #pragma unroll
            for (int j = 0; j < 4; ++j) { e4[j] = __expf(sc[j] - m); ssum += e4[j]; }
            ssum += __shfl_xor(ssum, 16);
            ssum += __shfl_xor(ssum, 32);
            float inv = 1.f / ssum;
            float* Pw = Pl + w * 240;
            if (lr < 12 && lg < 3) {
                f32x4 pvec = (f32x4){e4[0] * inv, e4[1] * inv, e4[2] * inv, e4[3] * inv};
                *(f32x4*)(Pw + lr * 20 + lg * 4) = pvec;
            }
            // same-wave P write -> read: no barrier needed (validated R5-R8)
            float vv[12];
            #pragma unroll
            for (int t = 0; t < 12; ++t) vv[t] = bf2f(Vt[lane * VS + rb + t]);
            #pragma unroll
            for (int ss = 0; ss < 12; ++ss) {
                f32x4 pa = *(const f32x4*)(Pw + ss * 20);
                f32x4 pb = *(const f32x4*)(Pw + ss * 20 + 4);
                f32x4 pc = *(const f32x4*)(Pw + ss * 20 + 8);
                float o = 0.f;
                #pragma unroll
                for (int t = 0; t < 4; ++t) o += pa[t] * vv[t];
                #pragma unroll
                for (int t = 0; t < 4; ++t) o += pb[t] * vv[4 + t];
                #pragma unroll
                for (int t = 0; t < 4; ++t) o += pc[t] * vv[8 + t];
                aout[(row0 + rb + ss) * (size_t)D_DIM + h * 64 + lane] = o;
            }
        }
        __syncthreads();   // A consumers done; safe to overwrite Q/K/V next head
    }
}

// ---------------- kernel 2: out-proj + bias + residual + LayerNorm (in-place) ----------------
__global__ __launch_bounds__(THREADS2) void oproj_ln(
    const float* __restrict__ x, const unsigned short* __restrict__ wt,
    const float* __restrict__ bo, const float* __restrict__ gamma,
    const float* __restrict__ beta, float* __restrict__ out)
{
    extern __shared__ char smem[];
    unsigned short* Ast = (unsigned short*)(smem + AST_OFF);  // [96][512] bf16
    float* red   = (float*)(smem + RED_OFF);   // [96][33]
    float* musig = (float*)(smem + MU_OFF);    // [96][2]

    const int tid  = threadIdx.x;
    const int lane = tid & 63;
    const int w    = tid >> 6;          // wave 0..15, cols [w*32, w*32+32)
    const int lr   = lane & 15;
    const int lg   = lane >> 4;
    const size_t row0 = (size_t)blockIdx.x * ROWS2;

    // stage A (f32 in out) -> LDS bf16 (swizzled); in-place safe (row-partitioned)
    #pragma unroll
    for (int it = 0; it < 12; ++it) {
        int idx = it * THREADS2 + tid;
        int r = idx >> 7, col = (idx & 127) << 2;
        float4 v = *(const float4*)(out + (row0 + r) * (size_t)D_DIM + col);
        ushort4 pk;
        pk.x = f2bf(v.x); pk.y = f2bf(v.y); pk.z = f2bf(v.z); pk.w = f2bf(v.w);
        *(ushort4*)(Ast + xswc(r, col)) = pk;
    }
    __syncthreads();

    f32x4 Y[6][2];
    #pragma unroll
    for (int mt = 0; mt < 6; ++mt)
        #pragma unroll
        for (int nt = 0; nt < 2; ++nt) Y[mt][nt] = (f32x4){0.f, 0.f, 0.f, 0.f};

    const unsigned short* obase = wt + (size_t)3 * WMAT + (w * 32 + lr) * D_DIM;
    #pragma unroll 2
    for (int ks = 0; ks < 16; ++ks) {
        bf16x8 afr[6];
        #pragma unroll
        for (int mt = 0; mt < 6; ++mt)
            afr[mt] = *(const bf16x8*)(Ast + xswc(mt * 16 + lr, ks * 32 + lg * 8));
        #pragma unroll
        for (int nt = 0; nt < 2; ++nt) {
            bf16x8 bfr = *(const bf16x8*)(obase + nt * 16 * D_DIM + ks * 32 + lg * 8);
            #pragma unroll
            for (int mt = 0; mt < 6; ++mt)
                Y[mt][nt] = __builtin_amdgcn_mfma_f32_16x16x32_bf16(afr[mt], bfr, Y[mt][nt], 0, 0, 0);
        }
    }

    // epilogue: +bo, +x (fp32), LayerNorm, store
    float bo2[2], gm2[2], bt2[2];
    int cols[2];
    #pragma unroll
    for (int nt = 0; nt < 2; ++nt) {
        cols[nt] = w * 32 + nt * 16 + lr;
        bo2[nt] = bo[cols[nt]]; gm2[nt] = gamma[cols[nt]]; bt2[nt] = beta[cols[nt]];
    }
    #pragma unroll
    for (int mt = 0; mt < 6; ++mt)
        #pragma unroll
        for (int j = 0; j < 4; ++j) {
            int rowl = mt * 16 + lg * 4 + j;
            const float* xrow = x + (row0 + rowl) * (size_t)D_DIM;
            float ps = 0.f, pq = 0.f;
            #pragma unroll
            for (int nt = 0; nt < 2; ++nt) {
                float y = Y[mt][nt][j] + bo2[nt] + xrow[cols[nt]];
                Y[mt][nt][j] = y;
                ps += y; pq += y * y;
            }
            ps += __shfl_xor(ps, 1); pq += __shfl_xor(pq, 1);
            ps += __shfl_xor(ps, 2); pq += __shfl_xor(pq, 2);
            ps += __shfl_xor(ps, 4); pq += __shfl_xor(pq, 4);
            ps += __shfl_xor(ps, 8); pq += __shfl_xor(pq, 8);
            if (lr == 0) { red[rowl * 33 + w * 2] = ps; red[rowl * 33 + w * 2 + 1] = pq; }
        }
    __syncthreads();
    if (tid < ROWS2) {
        float s = 0.f, q = 0.f;
        #pragma unroll
        for (int w16 = 0; w16 < 16; ++w16) { s += red[tid * 33 + w16 * 2]; q += red[tid * 33 + w16 * 2 + 1]; }
        float mu = s * (1.f / 512.f);
        float var = q * (1.f / 512.f) - mu * mu;
        musig[tid * 2] = mu;
        musig[tid * 2 + 1] = rsqrtf(var + 1e-5f);
    }
    __syncthreads();
    #pragma unroll
    for (int mt = 0; mt < 6; ++mt)
        #pragma unroll
        for (int j = 0; j < 4; ++j) {
            int rowl = mt * 16 + lg * 4 + j;
            float mu = musig[rowl * 2], rs = musig[rowl * 2 + 1];
            float* orow = out + (row0 + rowl) * (size_t)D_DIM;
            #pragma unroll
            for (int nt = 0; nt < 2; ++nt)
                orow[cols[nt]] = (Y[mt][nt][j] - mu) * rs * gm2[nt] + bt2[nt];
        }
}

extern "C" void kernel_launch(void* const* d_in, const int* in_sizes, int n_in,
                              void* d_out, int out_size, void* d_ws, size_t ws_size,
                              hipStream_t stream) {
    (void)in_sizes; (void)n_in; (void)out_size; (void)ws_size;
    const float* x     = (const float*)d_in[0];
    const float* Wq    = (const float*)d_in[1];
    const float* bq    = (const float*)d_in[2];
    const float* Wk    = (const float*)d_in[3];
    const float* bk    = (const float*)d_in[4];
    const float* Wv    = (const float*)d_in[5];
    const float* bv    = (const float*)d_in[6];
    const float* adj   = (const float*)d_in[7];
    const float* Wo    = (const float*)d_in[8];
    const float* bo    = (const float*)d_in[9];
    const float* gamma = (const float*)d_in[10];
    const float* beta  = (const float*)d_in[11];
    unsigned short* wt = (unsigned short*)d_ws;      // 4 * 512*512 bf16 = 2 MiB
    float* outf = (float*)d_out;

    prep_weights<<<4096, 256, 0, stream>>>(Wq, Wk, Wv, Wo, wt);
    qkv_attn<<<16384 / G_B1, THREADS1, SMEM1, stream>>>(x, wt, bq, bk, bv, adj, outf);
    oproj_ln<<<16384 / G_B2, THREADS2, SMEM2, stream>>>(x, wt, bo, gamma, beta, outf);
}